// Round 15
// baseline (182.751 us; speedup 1.0000x reference)
//
#include <hip/hip_runtime.h>
#include <stdint.h>

// Shapes (fixed): x [4,2048,1024] f32, qkv_w [3072,1024] f32, out_w [1024,1024] f32,
// out_b [1024] f32, out [4,2048,1024] f32.
// Pipeline: cvt->bf16 (fused), gemm8p<NI=3,QSC=1> qkv (256x192, grid 512),
// flash attn v4 (KVBLK=128: 17 tiles/block, K dbuf gld16 + V tribuf reg-staged,
// dist-1 prefetch with free drain, fixed-shift softmax, cross-tile PV),
// gemm8p<NI=2,f32+bias> out (256x128, grid 256).

typedef __bf16 bfx8 __attribute__((ext_vector_type(8)));
typedef float f32x4 __attribute__((ext_vector_type(4)));
typedef float f32x16 __attribute__((ext_vector_type(16)));

__device__ __forceinline__ uint16_t f2b(float f) {
  uint32_t u = __float_as_uint(f);
  u += 0x7fff + ((u >> 16) & 1);   // RNE
  return (uint16_t)(u >> 16);
}

__device__ __forceinline__ uint32_t cvt_pk(float lo, float hi) {
  uint32_t r;
  asm("v_cvt_pk_bf16_f32 %0, %1, %2" : "=v"(r) : "v"(lo), "v"(hi));
  return r;
}

__device__ __forceinline__ void gld16(const void* g, void* l) {
  __builtin_amdgcn_global_load_lds((const __attribute__((address_space(1))) void*)g,
                                   (__attribute__((address_space(3))) void*)l,
                                   16, 0, 0);
}

// ---------------- fused f32 -> bf16 convert (8 elems/thread, 3 tensors) -----------
__global__ __launch_bounds__(256) void cvt_all(const float* __restrict__ x,
                                               const float* __restrict__ w1,
                                               const float* __restrict__ w2,
                                               uint16_t* __restrict__ xb,
                                               uint16_t* __restrict__ w1b,
                                               uint16_t* __restrict__ w2b) {
  int i = blockIdx.x * 256 + threadIdx.x;
  const float* in;
  uint16_t* out;
  if (i < 1048576) { in = x; out = xb; }
  else if (i < 1048576 + 393216) { in = w1; out = w1b; i -= 1048576; }
  else { in = w2; out = w2b; i -= 1048576 + 393216; }
  float4 a = ((const float4*)in)[2 * i];
  float4 b = ((const float4*)in)[2 * i + 1];
  union { uint16_t u[8]; uint4 v; } pk;
  pk.u[0] = f2b(a.x); pk.u[1] = f2b(a.y); pk.u[2] = f2b(a.z); pk.u[3] = f2b(a.w);
  pk.u[4] = f2b(b.x); pk.u[5] = f2b(b.y); pk.u[6] = f2b(b.z); pk.u[7] = f2b(b.w);
  ((uint4*)out)[i] = pk.v;
}

// ---------------- gemm8p<NI,OUTF32,QSC>: C[M,N] = A[M,K]*B[N,K]^T (+bias) ---------
// BM=256, BN=64*NI, BK=64, 512 threads (8 waves 2x4). 4 phases/K-tile, counted
// vmcnt(4+NI). HW-proven r11-r14 structure. QSC=1: scale cols<1024 by 0.125*log2e.
template <int NI, int OUTF32, int QSC>
__global__ __launch_bounds__(512, 2) void gemm8p(const uint16_t* __restrict__ A,
                                                 const uint16_t* __restrict__ B,
                                                 void* __restrict__ Cout,
                                                 const float* __restrict__ bias,
                                                 int M, int N, int K, int nbx, int nwg) {
  constexpr int G0 = (NI + 1) / 2;
  constexpr int G1 = NI - G0;
  __shared__ alignas(16) uint16_t As[2][256 * 64];
  __shared__ alignas(16) uint16_t Bs[2][64 * NI * 64];

  int did = blockIdx.x;
  int wg = (did & 7) * (nwg >> 3) + (did >> 3);   // XCD swizzle (nwg % 8 == 0)
  int bx = wg % nbx, by = wg / nbx;
  int m0 = by * 256, n0 = bx * (64 * NI);

  int tid = threadIdx.x, lane = tid & 63, wid = tid >> 6;
  int wm = wid >> 2, wn = wid & 3;
  int l15 = lane & 15;
  int ko = (lane >> 4) * 8;
  int sw = (l15 & 7) * 8;

  int srow = lane >> 3;
  int scol = ((lane & 7) ^ srow) * 8;

  f32x4 acc[8][NI] = {};

  auto stageA = [&](int buf, int t) {
    int k0 = t * 64;
#pragma unroll
    for (int i = 0; i < 4; ++i) {
      int r = wid * 32 + i * 8;
      gld16(&A[(size_t)(m0 + r + srow) * K + k0 + scol], &As[buf][r * 64]);
    }
  };
  auto stageB = [&](int buf, int t) {
    int k0 = t * 64;
#pragma unroll
    for (int i = 0; i < NI; ++i) {
      int r = wid * 8 * NI + i * 8;
      gld16(&B[(size_t)(n0 + r + srow) * K + k0 + scol], &Bs[buf][r * 64]);
    }
  };
  auto waitSteady = [&]() {
    if constexpr (NI == 3) asm volatile("s_waitcnt vmcnt(7)" ::: "memory");
    else                   asm volatile("s_waitcnt vmcnt(6)" ::: "memory");
  };

  stageA(0, 0); stageB(0, 0);
  stageA(1, 1); stageB(1, 1);
  waitSteady();
  __builtin_amdgcn_s_barrier();
  __builtin_amdgcn_sched_barrier(0);

  int nt = K >> 6;
  for (int t = 0; t < nt; ++t) {
    int buf = t & 1;
    const uint16_t* ap = &As[buf][0];
    const uint16_t* bp = &Bs[buf][0];
    bfx8 a[4][2], bg0[G0][2], bg1[G1][2], a2[4][2];

    // P1: A-low + B-G0 -> Q(lo,G0)
#pragma unroll
    for (int mi = 0; mi < 4; ++mi)
#pragma unroll
      for (int kk = 0; kk < 2; ++kk) {
        int r = wm * 128 + mi * 16 + l15;
        a[mi][kk] = *(const bfx8*)&ap[r * 64 + ((kk * 32 + ko) ^ sw)];
      }
#pragma unroll
    for (int ni = 0; ni < G0; ++ni)
#pragma unroll
      for (int kk = 0; kk < 2; ++kk) {
        int r = wn * (NI * 16) + ni * 16 + l15;
        bg0[ni][kk] = *(const bfx8*)&bp[r * 64 + ((kk * 32 + ko) ^ sw)];
      }
    __builtin_amdgcn_s_barrier();
    __builtin_amdgcn_s_setprio(1);
#pragma unroll
    for (int mi = 0; mi < 4; ++mi)
#pragma unroll
      for (int ni = 0; ni < G0; ++ni)
#pragma unroll
        for (int kk = 0; kk < 2; ++kk)
          acc[mi][ni] = __builtin_amdgcn_mfma_f32_16x16x32_bf16(a[mi][kk], bg0[ni][kk],
                                                                acc[mi][ni], 0, 0, 0);
    __builtin_amdgcn_s_setprio(0);
    __builtin_amdgcn_s_barrier();

    // P2: B-G1 -> Q(lo,G1)
#pragma unroll
    for (int ni = 0; ni < G1; ++ni)
#pragma unroll
      for (int kk = 0; kk < 2; ++kk) {
        int r = wn * (NI * 16) + (G0 + ni) * 16 + l15;
        bg1[ni][kk] = *(const bfx8*)&bp[r * 64 + ((kk * 32 + ko) ^ sw)];
      }
    __builtin_amdgcn_s_barrier();
    __builtin_amdgcn_s_setprio(1);
#pragma unroll
    for (int mi = 0; mi < 4; ++mi)
#pragma unroll
      for (int ni = 0; ni < G1; ++ni)
#pragma unroll
        for (int kk = 0; kk < 2; ++kk)
          acc[mi][G0 + ni] = __builtin_amdgcn_mfma_f32_16x16x32_bf16(a[mi][kk], bg1[ni][kk],
                                                                     acc[mi][G0 + ni], 0, 0, 0);
    __builtin_amdgcn_s_setprio(0);
    __builtin_amdgcn_s_barrier();

    // P3: A-high; stage B(t+2) -> Q(hi,G0)
#pragma unroll
    for (int mi = 0; mi < 4; ++mi)
#pragma unroll
      for (int kk = 0; kk < 2; ++kk) {
        int r = wm * 128 + (mi + 4) * 16 + l15;
        a2[mi][kk] = *(const bfx8*)&ap[r * 64 + ((kk * 32 + ko) ^ sw)];
      }
    if (t + 2 < nt) stageB(buf, t + 2);
    __builtin_amdgcn_s_barrier();
    __builtin_amdgcn_s_setprio(1);
#pragma unroll
    for (int mi = 0; mi < 4; ++mi)
#pragma unroll
      for (int ni = 0; ni < G0; ++ni)
#pragma unroll
        for (int kk = 0; kk < 2; ++kk)
          acc[mi + 4][ni] = __builtin_amdgcn_mfma_f32_16x16x32_bf16(a2[mi][kk], bg0[ni][kk],
                                                                    acc[mi + 4][ni], 0, 0, 0);
    __builtin_amdgcn_s_setprio(0);
    __builtin_amdgcn_s_barrier();

    // P4: stage A(t+2); counted vmcnt -> Q(hi,G1)
    if (t + 2 < nt) {
      stageA(buf, t + 2);
      waitSteady();
    } else if (t + 2 == nt) {
      asm volatile("s_waitcnt vmcnt(0)" ::: "memory");
    }
    __builtin_amdgcn_sched_barrier(0);
    __builtin_amdgcn_s_barrier();
    __builtin_amdgcn_s_setprio(1);
#pragma unroll
    for (int mi = 0; mi < 4; ++mi)
#pragma unroll
      for (int ni = 0; ni < G1; ++ni)
#pragma unroll
        for (int kk = 0; kk < 2; ++kk)
          acc[mi + 4][G0 + ni] = __builtin_amdgcn_mfma_f32_16x16x32_bf16(a2[mi][kk], bg1[ni][kk],
                                                                         acc[mi + 4][G0 + ni], 0, 0, 0);
    __builtin_amdgcn_s_setprio(0);
    __builtin_amdgcn_s_barrier();
  }

#pragma unroll
  for (int mi = 0; mi < 8; ++mi) {
    int row = m0 + wm * 128 + mi * 16 + ((lane >> 4) << 2);
#pragma unroll
    for (int ni = 0; ni < NI; ++ni) {
      int col = n0 + wn * (NI * 16) + ni * 16 + l15;
      float qsc = (QSC && col < 1024) ? 0.18033688f : 1.0f;   // 0.125*log2(e)
#pragma unroll
      for (int r = 0; r < 4; ++r) {
        float v = acc[mi][ni][r];
        if (OUTF32)
          ((float*)Cout)[(size_t)(row + r) * N + col] = v + bias[col];
        else
          ((uint16_t*)Cout)[(size_t)(row + r) * N + col] = f2b(v * qsc);
      }
    }
  }
}

// ---------------- flash attention v4 (causal), KVBLK=128 ----------------
// 512 UNIFORM blocks: bh = d&63 (XCD L2 locality), a = d>>6; parts qb = 15-a then a.
// q0 = qb*128, ntile = qb+1 tiles of 128 kv -> total 17 tiles/block (uniform).
// 4 waves x 32 q. Per tile: 16 QK MFMA + 16 PV MFMA between ONE barrier (halved
// overhead vs KVBLK=64). K double-buffered via gld16 (4/wave); V triple-buffered,
// reg-staged b64 packed writes (PV of t-1 runs in t -> needs tri). Distance-1
// prefetch: loads issued a full tile (~5-10K cy) before the vmcnt(0) drain -> free.
// Fixed-shift softmax (Q pre-scaled by CSC in gemm1): p = exp2(S), no max tracking.
// LDS 80KB/block -> 2 blocks/CU (160KB exact). launch_bounds (256,2) (no VGPR cap:
// r6/r10 spill lessons).
__global__ __launch_bounds__(256, 2) void flash_attn(const uint16_t* __restrict__ qkv,
                                                     uint16_t* __restrict__ attnb) {
  const int T = 2048, D3 = 3072;
  __shared__ alignas(16) uint16_t Ks[2][128 * 64];   // [kv][hd], swizzled
  __shared__ alignas(16) uint16_t Vt[3][64 * 128];   // V^T: [hd][kv], swizzled

  int d = blockIdx.x;
  int bh = d & 63;
  int a = d >> 6;              // 0..7
  int b = bh >> 4, h = bh & 15;

  int tid = threadIdx.x, lane = tid & 63, wid = tid >> 6;
  int l31 = lane & 31, hi = lane >> 5;
  int swz = (lane & 7) << 3;

  size_t base = (size_t)b * T * D3;
  int hoff = h * 64;
  const uint16_t* kbase = &qkv[base + 1024 + hoff];
  const uint16_t* vbase = &qkv[base + 2048 + hoff];

  // K staging: wave covers rows wid*32..+31 (4 gld16 x 8 rows); pre-swizzled col
  int ksub = lane >> 3;                               // 0..7
  int kc = ((lane & 7) << 3) ^ (ksub << 3);
  // V staging: thread covers kv rows vr4..vr4+3 at hd cols vc..vc+7
  int vr4 = (tid & 31) * 4;
  int vc = (tid >> 5) * 8;

  for (int p = 0; p < 2; ++p) {
    int qb = (p == 0) ? (15 - a) : a;   // long part first
    int q0 = qb << 7;
    int qw = q0 + wid * 32;
    int ntile = qb + 1;

    float l_r = 0.f;
    f32x16 acc0 = {}, acc1 = {};
    bfx8 pf[8];
    int smax_prev = -1, vb_prev = 0;

    // Q frags (B-operand): col=q=l31, k = hd = 16*h4 + 8*hi + j  (pre-scaled)
    bfx8 qf[4];
    {
      const uint16_t* qp = &qkv[base + (size_t)(qw + l31) * D3 + hoff + 8 * hi];
#pragma unroll
      for (int h4 = 0; h4 < 4; ++h4) qf[h4] = *(const bfx8*)(qp + 16 * h4);
    }

    uint4 v0r, v1r, v2r, v3r;   // V staging regs (dist-1: single bank)

    auto loadV = [&](int kv0) {
      const uint16_t* vp = &vbase[(size_t)(kv0 + vr4) * D3 + vc];
      v0r = *(const uint4*)vp;
      v1r = *(const uint4*)(vp + D3);
      v2r = *(const uint4*)(vp + 2 * D3);
      v3r = *(const uint4*)(vp + 3 * D3);
    };
    auto stageK = [&](int buf, int kv0) {
#pragma unroll
      for (int i = 0; i < 4; ++i) {
        int r = wid * 32 + i * 8;
        gld16(&kbase[(size_t)(kv0 + r + ksub) * D3 + kc], &Ks[buf][r * 64]);
      }
    };
    auto writeV = [&](int vb) {
      union { uint4 v; uint16_t u[8]; } x0, x1, x2, x3;
      x0.v = v0r; x1.v = v1r; x2.v = v2r; x3.v = v3r;
#pragma unroll
      for (int j = 0; j < 8; ++j) {
        int hd = vc + j;
        uint2 val;
        val.x = (uint32_t)x0.u[j] | ((uint32_t)x1.u[j] << 16);
        val.y = (uint32_t)x2.u[j] | ((uint32_t)x3.u[j] << 16);
        *(uint2*)&Vt[vb][hd * 128 + (vr4 ^ ((hd & 7) << 3))] = val;
      }
    };
    auto doPV = [&]() {
      const uint16_t* vp = &Vt[vb_prev][0];
      __builtin_amdgcn_s_setprio(1);
#pragma unroll
      for (int s = 0; s < 8; ++s) {
        if (s <= smax_prev) {
          bfx8 va = *(const bfx8*)&vp[l31 * 128 + ((16 * s + 8 * hi) ^ swz)];
          acc0 = __builtin_amdgcn_mfma_f32_32x32x16_bf16(va, pf[s], acc0, 0, 0, 0);
          bfx8 vb2 = *(const bfx8*)&vp[(32 + l31) * 128 + ((16 * s + 8 * hi) ^ swz)];
          acc1 = __builtin_amdgcn_mfma_f32_32x32x16_bf16(vb2, pf[s], acc1, 0, 0, 0);
        }
      }
      __builtin_amdgcn_s_setprio(0);
    };

    // ---- prologue: stage tile 0; full drain ----
    loadV(0);
    stageK(0, 0);
    writeV(0);                 // compiler waits on V regs
    asm volatile("s_waitcnt vmcnt(0) lgkmcnt(0)" ::: "memory");
    __builtin_amdgcn_s_barrier();
    __builtin_amdgcn_sched_barrier(0);

    for (int t = 0; t < ntile; ++t) {
      int kv0 = t << 7;
      bool issue = (t + 1 < ntile);
      if (issue) {
        loadV((t + 1) << 7);                 // issued first (older in queue)
        stageK((t + 1) & 1, (t + 1) << 7);
      }
      bool active = (kv0 <= qw);
      int dq = qw - kv0;                      // valid when active
      int tmax = 4, sd = -1;
      if (active && dq < 128) { tmax = (dq >> 5) + 1; sd = dq >> 5; }
      f32x16 st[4] = {};

      if (active) {
        // ---- S^T = K * Q^T (up to 16 MFMA) ----
        const uint16_t* kp = &Ks[t & 1][0];
        __builtin_amdgcn_s_setprio(1);
#pragma unroll
        for (int h4 = 0; h4 < 4; ++h4) {
#pragma unroll
          for (int s = 0; s < 4; ++s) {
            if (s < tmax) {
              bfx8 kf = *(const bfx8*)&kp[(32 * s + l31) * 64 + ((16 * h4 + 8 * hi) ^ swz)];
              st[s] = __builtin_amdgcn_mfma_f32_32x32x16_bf16(kf, qf[h4], st[s], 0, 0, 0);
            }
          }
        }
        __builtin_amdgcn_s_setprio(0);
      }

      // ---- PV of PREVIOUS tile (frees pf; overlaps softmax chain) ----
      if (smax_prev >= 0) { doPV(); smax_prev = -1; }

      if (active) {
        int q = qw + l31;
        // mask diagonal sub-tile sd (kv > q); sub-tiles > sd never computed
#pragma unroll
        for (int s = 0; s < 4; ++s) {
          if (s == sd) {
#pragma unroll
            for (int r = 0; r < 16; ++r) {
              int kv = kv0 + 32 * s + (r & 3) + 8 * (r >> 2) + 4 * hi;
              if (kv > q) st[s][r] = -1e30f;
            }
          }
        }
        // fixed-shift: p = exp2(s) directly; per-lane l partials
        float l0 = 0.f, l1 = 0.f, l2 = 0.f, l3 = 0.f;
#pragma unroll
        for (int s = 0; s < 4; ++s) {
          if (s < tmax) {
#pragma unroll
            for (int r = 0; r < 16; r += 4) {
              float e0 = __builtin_amdgcn_exp2f(st[s][r]);
              float e1 = __builtin_amdgcn_exp2f(st[s][r + 1]);
              float e2 = __builtin_amdgcn_exp2f(st[s][r + 2]);
              float e3 = __builtin_amdgcn_exp2f(st[s][r + 3]);
              st[s][r] = e0; st[s][r + 1] = e1; st[s][r + 2] = e2; st[s][r + 3] = e3;
              l0 += e0; l1 += e1; l2 += e2; l3 += e3;
            }
          }
        }
        l_r += (l0 + l1) + (l2 + l3);

        // ---- pack P -> bf16 B-frags (slice s8 covers kv 16*s8..+15) ----
        int smax = (dq + 31) >> 4;
        if (smax > 7) smax = 7;
#pragma unroll
        for (int s8 = 0; s8 < 8; ++s8) {
          if (s8 <= smax) {
            int pb = 8 * (s8 & 1);
            const f32x16& src = st[s8 >> 1];   // compile-time index
            uint32_t W0 = cvt_pk(src[pb + 0], src[pb + 1]);
            uint32_t W1 = cvt_pk(src[pb + 2], src[pb + 3]);
            uint32_t W2 = cvt_pk(src[pb + 4], src[pb + 5]);
            uint32_t W3 = cvt_pk(src[pb + 6], src[pb + 7]);
            auto rA = __builtin_amdgcn_permlane32_swap(W0, W2, false, false);
            auto rB = __builtin_amdgcn_permlane32_swap(W1, W3, false, false);
            union { uint32_t u[4]; bfx8 v; } pk;
            pk.u[0] = rA[0]; pk.u[1] = rB[0]; pk.u[2] = rA[1]; pk.u[3] = rB[1];
            pf[s8] = pk.v;
          }
        }
        smax_prev = smax;
        vb_prev = t % 3;
      }

      if (issue) writeV((t + 1) % 3);   // V regs landed long ago; write before barrier

      asm volatile("s_waitcnt vmcnt(0) lgkmcnt(0)" ::: "memory");  // free: issued ~1 tile ago
      __builtin_amdgcn_s_barrier();
      __builtin_amdgcn_sched_barrier(0);
    }
    if (smax_prev >= 0) doPV();

    // ---- epilogue: merge l across lane pair, normalize, transpose, store ----
    float l_tot = l_r + __shfl_xor(l_r, 32);
    __syncthreads();   // all waves done with K/V LDS before overlay
    uint16_t* ow = ((uint16_t*)Ks) + wid * 2048;  // per-wave [32 q][64 hd] in Ks (32KB)
    float rl = 1.0f / l_tot;
#pragma unroll
    for (int f = 0; f < 2; ++f) {
#pragma unroll
      for (int r = 0; r < 16; r += 2) {
        int hd = 32 * f + (r & 3) + 8 * (r >> 2) + 4 * hi;
        float v0 = (f ? acc1[r] : acc0[r]) * rl;
        float v1 = (f ? acc1[r + 1] : acc0[r + 1]) * rl;
        *(uint32_t*)&ow[l31 * 64 + (hd ^ ((l31 & 7) << 3))] = cvt_pk(v0, v1);
      }
    }
    // wave-private region: no barrier between write and read
    int row = lane >> 1, cb = (lane & 1) * 32;
    int q = q0 + wid * 32 + row;
    int rs = (row & 7) << 3;
    uint16_t* dst = &attnb[(size_t)(b * T + q) * 1024 + hoff + cb];
#pragma unroll
    for (int cc = 0; cc < 4; ++cc)
      *(uint4*)&dst[cc * 8] = *(const uint4*)&ow[row * 64 + ((cb + cc * 8) ^ rs)];
    __syncthreads();   // epilogue reads done before next part restages
  }
}

// ---------------- host ----------------
extern "C" void kernel_launch(void* const* d_in, const int* in_sizes, int n_in,
                              void* d_out, int out_size, void* d_ws, size_t ws_size,
                              hipStream_t stream) {
  const float* x = (const float*)d_in[0];
  const float* qkv_w = (const float*)d_in[1];
  const float* out_w = (const float*)d_in[2];
  const float* out_b = (const float*)d_in[3];
  float* out = (float*)d_out;

  char* ws = (char*)d_ws;
  uint16_t* xb    = (uint16_t*)(ws);
  uint16_t* qkvb  = (uint16_t*)(ws + 16777216);
  uint16_t* attnb = (uint16_t*)(ws + 67108864);
  uint16_t* wqkvb = (uint16_t*)(ws + 83886080);
  uint16_t* wob   = (uint16_t*)(ws + 90177536);

  cvt_all<<<6144, 256, 0, stream>>>(x, qkv_w, out_w, xb, wqkvb, wob);

  // qkv = x @ qkv_w^T : M=8192 N=3072 K=1024, 256x192 tiles -> grid 32*16 = 512
  gemm8p<3, 0, 1><<<512, 512, 0, stream>>>(xb, wqkvb, (void*)qkvb, nullptr,
                                           8192, 3072, 1024, 16, 512);
  flash_attn<<<512, 256, 0, stream>>>(qkvb, attnb);
  // out = attn @ out_w^T + b : M=8192 N=1024 K=1024, 256x128 tiles -> grid 32*8 = 256
  gemm8p<2, 1, 0><<<256, 512, 0, stream>>>(attnb, wob, (void*)out, out_b,
                                           8192, 1024, 1024, 8, 256);
}